// Round 13
// baseline (1008.897 us; speedup 1.0000x reference)
//
#include <hip/hip_runtime.h>

// ---------------- problem constants ----------------
#define T_TOK 4096          // BB*L tokens
#define HID   2048
#define DI    4096
#define NH    64
#define PDIM  64
#define NSTATE 128
#define IM    8192
#define LSEQ  2048
#define CONVD 4352          // DI + 2*G*N
#define DPROJ 8512          // 2*DI + 2*G*N + NH
#define DPADR 8704          // padded to 34*256
#define QC    64            // SSD chunk length
#define NCH   32            // chunks per sequence

typedef __bf16 bf16x8 __attribute__((ext_vector_type(8)));
typedef float  f32x4  __attribute__((ext_vector_type(4)));
typedef float  f32x16 __attribute__((ext_vector_type(16)));

__device__ __forceinline__ unsigned short f2bf(float f) {
  unsigned u = __float_as_uint(f);
  u = (u + 0x7fffu + ((u >> 16) & 1u)) >> 16;
  return (unsigned short)u;
}
__device__ __forceinline__ float bf2f(unsigned short h) {
  return __uint_as_float(((unsigned)h) << 16);
}
__device__ __forceinline__ float siluf(float x) {
  return x / (1.f + __expf(-x));
}

#define GLL(gaddr, laddr) __builtin_amdgcn_global_load_lds( \
    (const __attribute__((address_space(1))) void*)(gaddr), \
    (__attribute__((address_space(3))) void*)(laddr), 16, 0, 0)

// ---------------- weight conversion helper (gid = 8-elem unit index) ----------------
__device__ __forceinline__ void cvt8(const float* __restrict__ s, unsigned short* __restrict__ d) {
  float4 v0 = *(const float4*)s;
  float4 v1 = *(const float4*)(s + 4);
  unsigned short o[8];
  o[0] = f2bf(v0.x); o[1] = f2bf(v0.y); o[2] = f2bf(v0.z); o[3] = f2bf(v0.w);
  o[4] = f2bf(v1.x); o[5] = f2bf(v1.y); o[6] = f2bf(v1.z); o[7] = f2bf(v1.w);
  *(uint4*)d = *(const uint4*)o;
}

// region thresholds in 8-elem units
#define CV_IN_END  2228224ULL   // DPADR*HID/8
#define CV_OUT_END 3276800ULL   // + 2048*4096/8
#define CV_GU_END  7471104ULL   // + 2*IM*2048/8
#define CV_DN_END  9568256ULL   // + 2048*8192/8

__device__ __forceinline__ void cvt_do(size_t gid,
    const float* __restrict__ w_in, const float* __restrict__ w_out,
    const float* __restrict__ w_gu, const float* __restrict__ w_dn,
    unsigned short* __restrict__ d_in, unsigned short* __restrict__ d_out,
    unsigned short* __restrict__ d_gu, unsigned short* __restrict__ d_dn) {
  if (gid < CV_IN_END) {
    size_t idx8 = gid * 8;
    int r = (int)(idx8 >> 11), k = (int)(idx8 & 2047);
    if (r < DPROJ) {
      cvt8(&w_in[(size_t)r * HID + k], d_in + idx8);
    } else {
      uint4 z = {0, 0, 0, 0};
      *(uint4*)(d_in + idx8) = z;
    }
  } else if (gid < CV_OUT_END) {
    size_t idx8 = (gid - CV_IN_END) * 8;
    cvt8(w_out + idx8, d_out + idx8);
  } else if (gid < CV_GU_END) {
    // gate_up: reorder rows so each 64-row group g = [gate g*32..+31 | up g*32..+31]
    size_t idx8 = (gid - CV_OUT_END) * 8;
    int r = (int)(idx8 >> 11), k = (int)(idx8 & 2047);
    int g = r >> 6, j = r & 63;
    int srcr = (j < 32) ? (g * 32 + j) : (IM + g * 32 + (j - 32));
    cvt8(&w_gu[(size_t)srcr * HID + k], d_gu + idx8);
  } else if (gid < CV_DN_END) {
    size_t idx8 = (gid - CV_GU_END) * 8;
    cvt8(w_dn + idx8, d_dn + idx8);
  }
}

// ---------------- pipelined BMx256 GEMM body, 32x32x16 MFMA ----------------
// C[M,N] = A[M,K] * W[N,K]^T, M fixed 4096. 512 thr = 8 waves (2M x 4N),
// per-wave (BM/2)x64 via (BM/64) x 2 blocks of 32x32, K-tile 64 = 4 ksteps.
// R5 loop structure (1 barrier + 1 vmcnt(0)/K-tile) kept verbatim — scheduling
// CLOSED (R6/R7/R10 all lost). Change vs R12: MFMA shape 16x16x32 -> 32x32x16
// (m119: 2495 vs 2176 TF matrix-pipe rate, ~-13% MFMA cycles, half the issues).
// Swizzle extended to 3 bits (byte bits 4-6 ^= row bits 2-4) on BOTH staging
// source and ds_read slot so 32-lane fragment reads keep 4 lanes/slot.
// C/D layout (m74/m101): col=lane&31, row=(reg&3)+8*(reg>>2)+4*(lane>>5).
// EPI: 0 = bf16 store, 1 = f32 + resid, 2 = gate-pair silu bf16, 3 = f32 store
template <int EPI, int BM>
__device__ __forceinline__ void gemm_body(int bid, int ngb,
    const unsigned short* __restrict__ A, const unsigned short* __restrict__ W,
    int K, int ldo, void* __restrict__ outp, const float* __restrict__ resid) {
  constexpr int MB    = BM / 64;          // 32-row blocks per wave
  constexpr int ABYT  = BM * 128;         // A region bytes per buffer
  constexpr int BUFB  = ABYT + 32768;     // buffer stride
  constexpr int NTM   = 4096 / BM;
  __shared__ __align__(16) char smem[2 * BUFB];
  const int t = threadIdx.x;
  const int w = t >> 6, l = t & 63;
  const int rl = l & 31, kh = l >> 5;     // fragment row-lane / k-half
  const int wr = w >> 2, wc = w & 3;

  // T1: bijective XCD swizzle over tn-major enumeration (ngb % 8 == 0)
  const int q = ngb >> 3;
  const int id2 = (bid & 7) * q + (bid >> 3);
  const int tn = id2 / NTM, tm = id2 % NTM;
  const int m0b = tm * BM, n0b = tn << 8;

  // staging: row = pass*64 + t>>3; source slot pre-swizzled (slot ^= row bits 2-4)
  const int srow = t >> 3;
  const int scole = (((t & 7) ^ ((t >> 5) & 7)) << 3);
  const unsigned short* Ag = A + (size_t)(m0b + srow) * K + scole;
  const unsigned short* Wg = W + (size_t)(n0b + srow) * K + scole;
  const int ldsw = w * 1024;

  // ds_read: byte addr = row*128 + ((2*ks + kh) ^ fx)*16, fx = row bits 2-4 (lane)
  const int fx = (l >> 2) & 7;
  int soff[4];
#pragma unroll
  for (int ks = 0; ks < 4; ks++) soff[ks] = ((2 * ks + kh) ^ fx) << 4;
  const int Aoff = (wr * (BM / 2) + rl) * 128;
  const int Boff = ABYT + (wc * 64 + rl) * 128;

#define ISSUE_A(jt, bb) do {                                                    \
    _Pragma("unroll")                                                           \
    for (int p_ = 0; p_ < BM / 64; ++p_)                                        \
      GLL(Ag + (size_t)(p_ * 64) * K + (size_t)(jt) * 64,                       \
          smem + (bb) * BUFB + p_ * 8192 + ldsw); } while (0)
#define ISSUE_B(jt, bb) do {                                                    \
    _Pragma("unroll")                                                           \
    for (int p_ = 0; p_ < 4; ++p_)                                              \
      GLL(Wg + (size_t)(p_ * 64) * K + (size_t)(jt) * 64,                       \
          smem + (bb) * BUFB + ABYT + p_ * 8192 + ldsw); } while (0)

#define RDF(off, base) (*(const bf16x8*)((base) + (off)))

  f32x16 acc[MB][2];
#pragma unroll
  for (int mb = 0; mb < MB; mb++)
#pragma unroll
    for (int nb = 0; nb < 2; nb++)
#pragma unroll
      for (int r = 0; r < 16; r++) acc[mb][nb][r] = 0.f;

  const int nkt = K >> 6;
  // prologue: stage tile 0 into buf 0
  ISSUE_A(0, 0); ISSUE_B(0, 0);

  for (int j = 0; j < nkt; ++j) {
    const int cur = j & 1;
    const char* Ab = smem + cur * BUFB;
    asm volatile("s_waitcnt vmcnt(0)" ::: "memory");   // waits loads issued a full tile ago
    __builtin_amdgcn_s_barrier();                       // all waves' slices resident (WAR-safe)
    __builtin_amdgcn_sched_barrier(0);
    if (j + 1 < nkt) { ISSUE_A(j + 1, cur ^ 1); ISSUE_B(j + 1, cur ^ 1); }
    bf16x8 bfr[2][4];
#pragma unroll
    for (int nb = 0; nb < 2; nb++)
#pragma unroll
      for (int ks = 0; ks < 4; ks++)
        bfr[nb][ks] = RDF(Boff + nb * 4096 + soff[ks], Ab);
#pragma unroll
    for (int mb = 0; mb < MB; mb++) {
      bf16x8 afr[4];
#pragma unroll
      for (int ks = 0; ks < 4; ks++)
        afr[ks] = RDF(Aoff + mb * 4096 + soff[ks], Ab);
#pragma unroll
      for (int ks = 0; ks < 4; ks++) {
        acc[mb][0] = __builtin_amdgcn_mfma_f32_32x32x16_bf16(afr[ks], bfr[0][ks], acc[mb][0], 0, 0, 0);
        acc[mb][1] = __builtin_amdgcn_mfma_f32_32x32x16_bf16(afr[ks], bfr[1][ks], acc[mb][1], 0, 0, 0);
      }
    }
  }

  // epilogue: C/D 32x32 layout: col = rl, row = (reg&3) + 8*(reg>>2) + 4*kh
  if constexpr (EPI == 0) {
    unsigned short* op = (unsigned short*)outp;
#pragma unroll
    for (int mb = 0; mb < MB; mb++)
#pragma unroll
      for (int nb = 0; nb < 2; nb++)
#pragma unroll
        for (int rq = 0; rq < 4; rq++)
#pragma unroll
          for (int r0 = 0; r0 < 4; r0++) {
            int row = m0b + wr * (BM / 2) + mb * 32 + rq * 8 + r0 + 4 * kh;
            int col = n0b + wc * 64 + nb * 32 + rl;
            op[(size_t)row * ldo + col] = f2bf(acc[mb][nb][rq * 4 + r0]);
          }
  } else if constexpr (EPI == 2) {
    unsigned short* op = (unsigned short*)outp;
    const int gbase = (n0b + wc * 64) >> 1;
#pragma unroll
    for (int mb = 0; mb < MB; mb++)
#pragma unroll
      for (int rq = 0; rq < 4; rq++)
#pragma unroll
        for (int r0 = 0; r0 < 4; r0++) {
          int row = m0b + wr * (BM / 2) + mb * 32 + rq * 8 + r0 + 4 * kh;
          int col = gbase + rl;
          float g = acc[mb][0][rq * 4 + r0], u = acc[mb][1][rq * 4 + r0];
          op[(size_t)row * ldo + col] = f2bf(siluf(g) * u);
        }
  } else {
    float* op = (float*)outp;
#pragma unroll
    for (int mb = 0; mb < MB; mb++)
#pragma unroll
      for (int nb = 0; nb < 2; nb++)
#pragma unroll
        for (int rq = 0; rq < 4; rq++)
#pragma unroll
          for (int r0 = 0; r0 < 4; r0++) {
            int row = m0b + wr * (BM / 2) + mb * 32 + rq * 8 + r0 + 4 * kh;
            int col = n0b + wc * 64 + nb * 32 + rl;
            float v = acc[mb][nb][rq * 4 + r0];
            if constexpr (EPI == 1) v += resid[(size_t)row * ldo + col];
            op[(size_t)row * ldo + col] = v;
          }
  }
#undef ISSUE_A
#undef ISSUE_B
#undef RDF
}

template <int EPI, int BM>
__global__ __launch_bounds__(512, 2)
void gemm8(const unsigned short* __restrict__ A, const unsigned short* __restrict__ W,
           int K, int ldo, void* __restrict__ outp, const float* __restrict__ resid) {
  gemm_body<EPI, BM>((int)blockIdx.x, (int)gridDim.x, A, W, K, ldo, outp, resid);
}

// in_proj GEMM fused with out/gu/dn weight conversion (blocks >= ngb do cvt)
__global__ __launch_bounds__(512, 2)
void k_inproj_fused(const unsigned short* __restrict__ A, const unsigned short* __restrict__ Wbf,
                    int ngb, unsigned short* __restrict__ projbf,
                    const float* __restrict__ w_out, const float* __restrict__ w_gu,
                    const float* __restrict__ w_dn, unsigned short* __restrict__ d_out,
                    unsigned short* __restrict__ d_gu, unsigned short* __restrict__ d_dn) {
  if ((int)blockIdx.x < ngb) {
    gemm_body<0, 256>((int)blockIdx.x, ngb, A, Wbf, HID, DPADR, projbf, nullptr);
  } else {
    size_t gid = CV_IN_END + (size_t)((int)blockIdx.x - ngb) * 512 + threadIdx.x;
    cvt_do(gid, nullptr, w_out, w_gu, w_dn, nullptr, d_out, d_gu, d_dn);
  }
}

// ---------------- norms ----------------
__device__ __forceinline__ float block_reduce_sum256(float v, float* sred) {
#pragma unroll
  for (int m = 32; m; m >>= 1) v += __shfl_xor(v, m);
  int t = threadIdx.x;
  if ((t & 63) == 0) sred[t >> 6] = v;
  __syncthreads();
  return sred[0] + sred[1] + sred[2] + sred[3];
}

// addnorm fused with in_proj weight conversion (blocks >= T_TOK do cvt)
__global__ __launch_bounds__(256)
void k_addnorm(const float* __restrict__ hin, const float* __restrict__ rin,
               const float* __restrict__ wln, float* __restrict__ rout,
               unsigned short* __restrict__ hbf,
               const float* __restrict__ w_in, unsigned short* __restrict__ d_in) {
  if ((int)blockIdx.x >= T_TOK) {
    size_t gid = (size_t)((int)blockIdx.x - T_TOK) * 256 + threadIdx.x;
    cvt_do(gid, w_in, nullptr, nullptr, nullptr, d_in, nullptr, nullptr, nullptr);
    return;
  }
  __shared__ float sred[4];
  const int tok = blockIdx.x, t = threadIdx.x;
  const size_t base = (size_t)tok * HID + t * 8;
  float4 a0 = *(const float4*)&hin[base];
  float4 a1 = *(const float4*)&hin[base + 4];
  float4 b0 = *(const float4*)&rin[base];
  float4 b1 = *(const float4*)&rin[base + 4];
  float v[8] = {a0.x + b0.x, a0.y + b0.y, a0.z + b0.z, a0.w + b0.w,
                a1.x + b1.x, a1.y + b1.y, a1.z + b1.z, a1.w + b1.w};
  float ss = 0.f;
#pragma unroll
  for (int j = 0; j < 8; j++) ss += v[j] * v[j];
  float tot = block_reduce_sum256(ss, sred);
  float rms = rsqrtf(tot * (1.f / HID) + 1e-5f);
  *(float4*)&rout[base] = (float4){v[0], v[1], v[2], v[3]};
  *(float4*)&rout[base + 4] = (float4){v[4], v[5], v[6], v[7]};
  float4 w0 = *(const float4*)&wln[t * 8];
  float4 w1 = *(const float4*)&wln[t * 8 + 4];
  float wa[8] = {w0.x, w0.y, w0.z, w0.w, w1.x, w1.y, w1.z, w1.w};
  unsigned short o[8];
#pragma unroll
  for (int j = 0; j < 8; j++) o[j] = f2bf(v[j] * rms * wa[j]);
  *(ushort4*)&hbf[base] = *(ushort4*)&o[0];
  *(ushort4*)&hbf[base + 4] = *(ushort4*)&o[4];
}

__global__ __launch_bounds__(256)
void k_rmsnorm_bf(const float* __restrict__ src, const float* __restrict__ wln,
                  unsigned short* __restrict__ dst) {
  __shared__ float sred[4];
  const int tok = blockIdx.x, t = threadIdx.x;
  const size_t base = (size_t)tok * HID + t * 8;
  float4 a0 = *(const float4*)&src[base];
  float4 a1 = *(const float4*)&src[base + 4];
  float v[8] = {a0.x, a0.y, a0.z, a0.w, a1.x, a1.y, a1.z, a1.w};
  float ss = 0.f;
#pragma unroll
  for (int j = 0; j < 8; j++) ss += v[j] * v[j];
  float tot = block_reduce_sum256(ss, sred);
  float rms = rsqrtf(tot * (1.f / HID) + 1e-5f);
  float4 w0 = *(const float4*)&wln[t * 8];
  float4 w1 = *(const float4*)&wln[t * 8 + 4];
  float wa[8] = {w0.x, w0.y, w0.z, w0.w, w1.x, w1.y, w1.z, w1.w};
  unsigned short o[8];
#pragma unroll
  for (int j = 0; j < 8; j++) o[j] = f2bf(v[j] * rms * wa[j]);
  *(ushort4*)&dst[base] = *(ushort4*)&o[0];
  *(ushort4*)&dst[base + 4] = *(ushort4*)&o[4];
}

__global__ __launch_bounds__(256)
void k_gatenorm(const unsigned short* __restrict__ ybuf, const unsigned short* __restrict__ projbf,
                const float* __restrict__ wmix, unsigned short* __restrict__ ynorm) {
  __shared__ float sred[4];
  const int tok = blockIdx.x, t = threadIdx.x;
  const size_t yb = (size_t)tok * DI;
  const size_t pb = (size_t)tok * DPADR;
  float g[16];
  float ss = 0.f;
#pragma unroll
  for (int j = 0; j < 16; j++) {
    int idx = j * 256 + t;
    float yv = bf2f(ybuf[yb + idx]);
    float z = bf2f(projbf[pb + idx]);
    float gg = yv * siluf(z);
    g[j] = gg;
    ss += gg * gg;
  }
  float tot = block_reduce_sum256(ss, sred);
  float rms = rsqrtf(tot * (1.f / DI) + 1e-5f);
#pragma unroll
  for (int j = 0; j < 16; j++) {
    int idx = j * 256 + t;
    ynorm[yb + idx] = f2bf(g[j] * rms * wmix[idx]);
  }
}

// ---------------- conv (depthwise causal K=4) + silu + fused dt softplus ----------------
__global__ __launch_bounds__(256)
void k_conv(const unsigned short* __restrict__ projbf, const float* __restrict__ cw,
            const float* __restrict__ cb, const float* __restrict__ dt_bias,
            unsigned short* __restrict__ xbf, unsigned short* __restrict__ bcbf,
            float* __restrict__ dtg) {
  const int c = blockIdx.x * 256 + threadIdx.x;   // 0..4607
  const int tk = blockIdx.y;                      // token
  if (c < CONVD) {
    const int lpos = tk & (LSEQ - 1);
    float4 wv = *(const float4*)&cw[c * 4];
    float wk[4] = {wv.x, wv.y, wv.z, wv.w};
    float acc = cb[c];
#pragma unroll
    for (int k = 0; k < 4; k++) {
      int lp = lpos - 3 + k;
      if (lp >= 0) acc += bf2f(projbf[(size_t)(tk - 3 + k) * DPADR + DI + c]) * wk[k];
    }
    unsigned short r = f2bf(siluf(acc));
    if (c < DI) xbf[(size_t)tk * DI + c] = r;
    else        bcbf[(size_t)tk * 256 + (c - DI)] = r;
  } else if (c < CONVD + NH) {
    const int hh = c - CONVD;
    float x = bf2f(projbf[(size_t)tk * DPADR + DI + c]) + dt_bias[hh];
    float dt = (x > 20.f) ? x : log1pf(__expf(x));
    dtg[(size_t)tk * NH + hh] = dt;
  }
}

// ---------------- SSD kernel 1: per (b,h,chunk) intra + chunk-state ----------------
__global__ __launch_bounds__(256)
void k_ssd1(const unsigned short* __restrict__ xbf, const unsigned short* __restrict__ bcbf,
            const float* __restrict__ dtg, const float* __restrict__ A_log,
            const float* __restrict__ Dv, unsigned short* __restrict__ ybuf,
            unsigned short* __restrict__ Sc, float* __restrict__ dtsum) {
  __shared__ __align__(16) char smem[60928];
  unsigned short* sBs  = (unsigned short*)(smem);          // [64][128]
  unsigned short* sCs  = (unsigned short*)(smem + 16384);  // [64][128]
  unsigned short* sMs  = (unsigned short*)(smem + 16384);  // alias: [64][72]
  unsigned short* sBsT = (unsigned short*)(smem + 32768);  // [128][72] scaled B^T
  unsigned short* sXsT = (unsigned short*)(smem + 51200);  // [64][72]  x^T
  float* sdt = (float*)(smem + 60416);
  float* sdl = (float*)(smem + 60672);

  const int bi = blockIdx.x;
  const int ch = bi & 31, h = (bi >> 5) & 63, b = bi >> 11;
  const int bh = b * NH + h;
  const int tok0 = b * LSEQ + ch * QC;
  const int t = threadIdx.x;
  const int w = t >> 6, l = t & 63, lr = l & 15, hi = l >> 4;
  const float Ah = -__expf(A_log[h]);
  const float Dh = Dv[h];

  {
    const int srow = t >> 4, scol = (t & 15) * 8;
#pragma unroll
    for (int i = 0; i < 4; i++) {
      const unsigned short* gb = bcbf + (size_t)(tok0 + srow + 16 * i) * 256 + scol;
      GLL(gb, (char*)sBs + i * 4096 + w * 1024);
      GLL(gb + 128, (char*)sCs + i * 4096 + w * 1024);
    }
  }
  if (t < QC) sdt[t] = dtg[(size_t)(tok0 + t) * NH + h];
  __syncthreads();
  if (t < QC) sdl[t] = sdt[t];
  __syncthreads();
  for (int off = 1; off < QC; off <<= 1) {
    float v = 0.f;
    if (t < QC && t >= off) v = sdl[t - off];
    __syncthreads();
    if (t < QC) sdl[t] += v;
    __syncthreads();
  }

  {
    const int s = t >> 2;
    const float DlQ = sdl[QC - 1];
    const float csc = __expf(Ah * (DlQ - sdl[s])) * sdt[s];
    const int n0 = (t & 3) * 32;
#pragma unroll
    for (int j = 0; j < 32; j++) {
      float bv = bf2f(sBs[s * 128 + n0 + j]);
      sBsT[(n0 + j) * 72 + s] = f2bf(csc * bv);
    }
    const int p0 = (t & 3) * 16;
    const unsigned short* gx = xbf + (size_t)(tok0 + s) * DI + h * 64 + p0;
    union { uint4 v; unsigned short u[8]; } x0, x1;
    x0.v = *(const uint4*)gx;
    x1.v = *(const uint4*)(gx + 8);
#pragma unroll
    for (int j = 0; j < 8; j++) {
      sXsT[(p0 + j) * 72 + s] = x0.u[j];
      sXsT[(p0 + 8 + j) * 72 + s] = x1.u[j];
    }
  }
  __syncthreads();

  f32x4 accS[4];
#pragma unroll
  for (int jf = 0; jf < 4; jf++) accS[jf] = (f32x4){0.f, 0.f, 0.f, 0.f};
#pragma unroll
  for (int ks = 0; ks < 4; ks++) {
    bf16x8 a = *(const bf16x8*)&sBs[(w * 16 + lr) * 128 + ks * 32 + hi * 8];
#pragma unroll
    for (int jf = 0; jf < 4; jf++) {
      bf16x8 bbq = *(const bf16x8*)&sCs[(jf * 16 + lr) * 128 + ks * 32 + hi * 8];
      accS[jf] = __builtin_amdgcn_mfma_f32_16x16x32_bf16(a, bbq, accS[jf], 0, 0, 0);
    }
  }
  __syncthreads();

  {
    const int s0 = w * 16 + hi * 4;
#pragma unroll
    for (int jf = 0; jf < 4; jf++) {
      const int tt = jf * 16 + lr;
      const float dlt = sdl[tt];
      unsigned short mv[4];
#pragma unroll
      for (int r = 0; r < 4; r++) {
        const int ss = s0 + r;
        float val = 0.f;
        if (ss <= tt) val = accS[jf][r] * __expf(Ah * (dlt - sdl[ss])) * sdt[ss];
        mv[r] = f2bf(val);
      }
      *(ushort4*)&sMs[tt * 72 + s0] = *(ushort4*)mv;
    }
  }
  __syncthreads();

  {
    f32x4 accY[4];
#pragma unroll
    for (int jf = 0; jf < 4; jf++) accY[jf] = (f32x4){0.f, 0.f, 0.f, 0.f};
#pragma unroll
    for (int ks = 0; ks < 2; ks++) {
      bf16x8 a = *(const bf16x8*)&sMs[(w * 16 + lr) * 72 + ks * 32 + hi * 8];
#pragma unroll
      for (int jf = 0; jf < 4; jf++) {
        bf16x8 bbq = *(const bf16x8*)&sXsT[(jf * 16 + lr) * 72 + ks * 32 + hi * 8];
        accY[jf] = __builtin_amdgcn_mfma_f32_16x16x32_bf16(a, bbq, accY[jf], 0, 0, 0);
      }
    }
#pragma unroll
    for (int jf = 0; jf < 4; jf++)
#pragma unroll
      for (int r = 0; r < 4; r++) {
        const int tt = w * 16 + hi * 4 + r;
        const int pp = jf * 16 + lr;
        float xv = bf2f(sXsT[pp * 72 + tt]);
        ybuf[(size_t)(tok0 + tt) * DI + h * 64 + pp] = f2bf(accY[jf][r] + Dh * xv);
      }
  }

  {
    f32x4 accT[8];
#pragma unroll
    for (int jf = 0; jf < 8; jf++) accT[jf] = (f32x4){0.f, 0.f, 0.f, 0.f};
#pragma unroll
    for (int ks = 0; ks < 2; ks++) {
      bf16x8 a = *(const bf16x8*)&sXsT[(w * 16 + lr) * 72 + ks * 32 + hi * 8];
#pragma unroll
      for (int jf = 0; jf < 8; jf++) {
        bf16x8 bbq = *(const bf16x8*)&sBsT[(jf * 16 + lr) * 72 + ks * 32 + hi * 8];
        accT[jf] = __builtin_amdgcn_mfma_f32_16x16x32_bf16(a, bbq, accT[jf], 0, 0, 0);
      }
    }
    unsigned short* sc = Sc + ((size_t)bh * NCH + ch) * (PDIM * NSTATE);
#pragma unroll
    for (int jf = 0; jf < 8; jf++)
#pragma unroll
      for (int r = 0; r < 4; r++) {
        const int pp = w * 16 + hi * 4 + r;
        const int nn = jf * 16 + lr;
        sc[pp * NSTATE + nn] = f2bf(accT[jf][r]);
      }
  }
  if (t == 0) dtsum[bh * NCH + ch] = sdl[QC - 1];
}

// ---------------- SSD kernel 2: serial chunk-state combine ----------------
__global__ __launch_bounds__(256)
void k_ssd2(const float* __restrict__ A_log, const float* __restrict__ dtsum,
            unsigned short* __restrict__ ScHt) {
  const int blk = blockIdx.x;
  const int bh = blk >> 3, pg = blk & 7;
  const int t = threadIdx.x;
  const int p = pg * 8 + (t >> 5), n0 = (t & 31) * 4;
  const int h = bh & 63;
  const float Ah = -__expf(A_log[h]);
  float H[4] = {0.f, 0.f, 0.f, 0.f};
  for (int c = 0; c < NCH; c++) {
    size_t base = (((size_t)bh * NCH + c) * PDIM + p) * NSTATE + n0;
    ushort4 sv = *(const ushort4*)&ScHt[base];
    float dec = __expf(Ah * dtsum[bh * NCH + c]);
    ushort4 hv;
    hv.x = f2bf(H[0]); hv.y = f2bf(H[1]); hv.z = f2bf(H[2]); hv.w = f2bf(H[3]);
    *(ushort4*)&ScHt[base] = hv;
    H[0] = dec * H[0] + bf2f(sv.x);
    H[1] = dec * H[1] + bf2f(sv.y);
    H[2] = dec * H[2] + bf2f(sv.z);
    H[3] = dec * H[3] + bf2f(sv.w);
  }
}

// ---------------- SSD kernel 3: inter-chunk Y += decay * C @ H_in ----------------
__global__ __launch_bounds__(256)
void k_ssd3(const unsigned short* __restrict__ bcbf, const unsigned short* __restrict__ Ht,
            const float* __restrict__ dtg, const float* __restrict__ A_log,
            unsigned short* __restrict__ ybuf) {
  __shared__ __align__(16) char smem[33280];
  unsigned short* sCs = (unsigned short*)(smem);
  unsigned short* sHt = (unsigned short*)(smem + 16384);
  float* sdt = (float*)(smem + 32768);
  float* sdl = (float*)(smem + 33024);

  const int bi = blockIdx.x;
  const int ch = bi & 31, h = (bi >> 5) & 63, b = bi >> 11;
  const int bh = b * NH + h;
  const int tok0 = b * LSEQ + ch * QC;
  const int t = threadIdx.x;
  const int w = t >> 6, l = t & 63, lr = l & 15, hi = l >> 4;
  const float Ah = -__expf(A_log[h]);

  {
    const int srow = t >> 4, scol = (t & 15) * 8;
    const unsigned short* gh = Ht + ((size_t)bh * NCH + ch) * (PDIM * NSTATE);
#pragma unroll
    for (int i = 0; i < 4; i++) {
      const unsigned short* gc = bcbf + (size_t)(tok0 + srow + 16 * i) * 256 + 128 + scol;
      GLL(gc, (char*)sCs + i * 4096 + w * 1024);
      GLL(gh + i * 2048 + t * 8, (char*)sHt + i * 4096 + w * 1024);
    }
  }
  if (t < QC) sdt[t] = dtg[(size_t)(tok0 + t) * NH + h];
  __syncthreads();
  if (t < QC) sdl[t] = sdt[t];
  __syncthreads();
  for (int off = 1; off < QC; off <<= 1) {
    float v = 0.f;
    if (t < QC && t >= off) v = sdl[t - off];
    __syncthreads();
    if (t < QC) sdl[t] += v;
    __syncthreads();
  }

  f32x4 acc[4];
#pragma unroll
  for (int jf = 0; jf < 4; jf++) acc[jf] = (f32x4){0.f, 0.f, 0.f, 0.f};
#pragma unroll
  for (int ks = 0; ks < 4; ks++) {
    bf16x8 a = *(const bf16x8*)&sCs[(w * 16 + lr) * 128 + ks * 32 + hi * 8];
#pragma unroll
    for (int jf = 0; jf < 4; jf++) {
      bf16x8 bbq = *(const bf16x8*)&sHt[(jf * 16 + lr) * 128 + ks * 32 + hi * 8];
      acc[jf] = __builtin_amdgcn_mfma_f32_16x16x32_bf16(a, bbq, acc[jf], 0, 0, 0);
    }
  }
#pragma unroll
  for (int jf = 0; jf < 4; jf++)
#pragma unroll
    for (int r = 0; r < 4; r++) {
      const int tt = w * 16 + hi * 4 + r;
      const int pp = jf * 16 + lr;
      const float dec = __expf(Ah * sdl[tt]);
      const size_t o = (size_t)(tok0 + tt) * DI + h * 64 + pp;
      ybuf[o] = f2bf(bf2f(ybuf[o]) + dec * acc[jf][r]);
    }
}

// ---------------- workspace layout (bytes), total ~412.1 MB ----------------
static const size_t OFF_WBF_IN  = 0;
static const size_t OFF_WBF_OUT = 35651584;
static const size_t OFF_WBF_GU  = 52428800;
static const size_t OFF_WBF_DN  = 119537664;
static const size_t OFF_RESID   = 153092096;
static const size_t OFF_HSBF    = 186646528;
static const size_t OFF_PROJ    = 203423744;
static const size_t OFF_XBF     = 274726912;
static const size_t OFF_BCBF    = 308281344;
static const size_t OFF_DTG     = 310378496;
static const size_t OFF_YBUF    = 311427072;
static const size_t OFF_SC      = 344981504;
static const size_t OFF_DTSUM   = 412090368;

extern "C" void kernel_launch(void* const* d_in, const int* in_sizes, int n_in,
                              void* d_out, int out_size, void* d_ws, size_t ws_size,
                              hipStream_t stream) {
  (void)in_sizes; (void)n_in; (void)out_size; (void)ws_size;
  const float* hidden   = (const float*)d_in[1];
  const float* resin    = (const float*)d_in[2];
  const float* w_inproj = (const float*)d_in[3];
  const float* conv_w   = (const float*)d_in[4];
  const float* conv_b   = (const float*)d_in[5];
  const float* A_log    = (const float*)d_in[6];
  const float* Dvec     = (const float*)d_in[7];
  const float* dt_bias  = (const float*)d_in[8];
  const float* w_mix    = (const float*)d_in[9];
  const float* w_outp   = (const float*)d_in[10];
  const float* w_ln1    = (const float*)d_in[11];
  const float* w_ln2    = (const float*)d_in[12];
  const float* w_gu     = (const float*)d_in[13];
  const float* w_dn     = (const float*)d_in[14];

  char* ws = (char*)d_ws;
  unsigned short* wbf_in  = (unsigned short*)(ws + OFF_WBF_IN);
  unsigned short* wbf_out = (unsigned short*)(ws + OFF_WBF_OUT);
  unsigned short* wbf_gu  = (unsigned short*)(ws + OFF_WBF_GU);
  unsigned short* wbf_dn  = (unsigned short*)(ws + OFF_WBF_DN);
  float*          residb  = (float*)(ws + OFF_RESID);
  unsigned short* hsbf    = (unsigned short*)(ws + OFF_HSBF);
  unsigned short* projbf  = (unsigned short*)(ws + OFF_PROJ);
  unsigned short* actbf   = (unsigned short*)(ws + OFF_PROJ);   // alias
  unsigned short* xbf     = (unsigned short*)(ws + OFF_XBF);
  unsigned short* ynormbf = (unsigned short*)(ws + OFF_XBF);    // alias
  unsigned short* bcbf    = (unsigned short*)(ws + OFF_BCBF);
  float*          dtgb    = (float*)(ws + OFF_DTG);
  unsigned short* ybuf    = (unsigned short*)(ws + OFF_YBUF);
  unsigned short* scht    = (unsigned short*)(ws + OFF_SC);
  float*          dtsumb  = (float*)(ws + OFF_DTSUM);

  float* out0 = (float*)d_out;
  float* res2 = out0 + (size_t)T_TOK * HID;

  // 1) residual add + input rmsnorm, fused with in_proj weight cvt
  k_addnorm<<<T_TOK + 8704, 256, 0, stream>>>(hidden, resin, w_ln1, residb, hsbf,
                                              w_inproj, wbf_in);
  // 2) in_proj GEMM (544 blocks) fused with out/gu/dn weight cvt (14336 blocks)
  k_inproj_fused<<<544 + 14336, 512, 0, stream>>>(hsbf, wbf_in, 544, projbf,
                                                  w_outp, w_gu, w_dn,
                                                  wbf_out, wbf_gu, wbf_dn);
  // 3) causal conv + silu -> xbf / bcbf (bf16), fused dt softplus
  k_conv<<<dim3(18, T_TOK), 256, 0, stream>>>(projbf, conv_w, conv_b, dt_bias, xbf, bcbf, dtgb);
  // 4) SSD intra + chunk states
  k_ssd1<<<4096, 256, 0, stream>>>(xbf, bcbf, dtgb, A_log, Dvec, ybuf, scht, dtsumb);
  // 5) SSD serial combine
  k_ssd2<<<1024, 256, 0, stream>>>(A_log, dtsumb, scht);
  // 6) SSD inter-chunk
  k_ssd3<<<4096, 256, 0, stream>>>(bcbf, scht, dtgb, A_log, ybuf);
  // 7) gate + mixer rmsnorm -> ynorm bf16
  k_gatenorm<<<T_TOK, 256, 0, stream>>>(ybuf, projbf, w_mix, ynormbf);
  // 8) out_proj GEMM + residual -> residual2 (output 1)
  gemm8<1, 128><<<8 * 32, 512, 0, stream>>>(ynormbf, wbf_out, DI, HID, res2, residb);
  // 9) pre-FF rmsnorm -> hs2 bf16
  k_rmsnorm_bf<<<T_TOK, 256, 0, stream>>>(res2, w_ln2, hsbf);
  // 10) gate_up GEMM (fused silu-pair epilogue) -> act bf16
  gemm8<2, 256><<<64 * 16, 512, 0, stream>>>(hsbf, wbf_gu, HID, IM, actbf, nullptr);
  // 11) down GEMM -> out (output 0)
  gemm8<3, 128><<<8 * 32, 512, 0, stream>>>(actbf, wbf_dn, IM, HID, out0, nullptr);
}

// Round 14
// 986.953 us; speedup vs baseline: 1.0222x; 1.0222x over previous
//
#include <hip/hip_runtime.h>

// ---------------- problem constants ----------------
#define T_TOK 4096          // BB*L tokens
#define HID   2048
#define DI    4096
#define NH    64
#define PDIM  64
#define NSTATE 128
#define IM    8192
#define LSEQ  2048
#define CONVD 4352          // DI + 2*G*N
#define DPROJ 8512          // 2*DI + 2*G*N + NH
#define DPADR 8704          // padded to 34*256
#define QC    64            // SSD chunk length
#define NCH   32            // chunks per sequence

typedef __bf16 bf16x8 __attribute__((ext_vector_type(8)));
typedef float  f32x4  __attribute__((ext_vector_type(4)));

__device__ __forceinline__ unsigned short f2bf(float f) {
  unsigned u = __float_as_uint(f);
  u = (u + 0x7fffu + ((u >> 16) & 1u)) >> 16;
  return (unsigned short)u;
}
__device__ __forceinline__ float bf2f(unsigned short h) {
  return __uint_as_float(((unsigned)h) << 16);
}
__device__ __forceinline__ float siluf(float x) {
  return x / (1.f + __expf(-x));
}

#define GLL(gaddr, laddr) __builtin_amdgcn_global_load_lds( \
    (const __attribute__((address_space(1))) void*)(gaddr), \
    (__attribute__((address_space(3))) void*)(laddr), 16, 0, 0)

// ---------------- weight conversion helper (gid = 8-elem unit index) ----------------
__device__ __forceinline__ void cvt8(const float* __restrict__ s, unsigned short* __restrict__ d) {
  float4 v0 = *(const float4*)s;
  float4 v1 = *(const float4*)(s + 4);
  unsigned short o[8];
  o[0] = f2bf(v0.x); o[1] = f2bf(v0.y); o[2] = f2bf(v0.z); o[3] = f2bf(v0.w);
  o[4] = f2bf(v1.x); o[5] = f2bf(v1.y); o[6] = f2bf(v1.z); o[7] = f2bf(v1.w);
  *(uint4*)d = *(const uint4*)o;
}

// region thresholds in 8-elem units
#define CV_IN_END  2228224ULL   // DPADR*HID/8
#define CV_OUT_END 3276800ULL   // + 2048*4096/8
#define CV_GU_END  7471104ULL   // + 2*IM*2048/8
#define CV_DN_END  9568256ULL   // + 2048*8192/8

__device__ __forceinline__ void cvt_do(size_t gid,
    const float* __restrict__ w_in, const float* __restrict__ w_out,
    const float* __restrict__ w_gu, const float* __restrict__ w_dn,
    unsigned short* __restrict__ d_in, unsigned short* __restrict__ d_out,
    unsigned short* __restrict__ d_gu, unsigned short* __restrict__ d_dn) {
  if (gid < CV_IN_END) {
    // in_proj: [8512,2048] -> [8704,2048], pad rows zero
    size_t idx8 = gid * 8;
    int r = (int)(idx8 >> 11), k = (int)(idx8 & 2047);
    if (r < DPROJ) {
      cvt8(&w_in[(size_t)r * HID + k], d_in + idx8);
    } else {
      uint4 z = {0, 0, 0, 0};
      *(uint4*)(d_in + idx8) = z;
    }
  } else if (gid < CV_OUT_END) {
    size_t idx8 = (gid - CV_IN_END) * 8;
    cvt8(w_out + idx8, d_out + idx8);
  } else if (gid < CV_GU_END) {
    // gate_up: reorder rows so each 64-row group g = [gate g*32..+31 | up g*32..+31]
    size_t idx8 = (gid - CV_OUT_END) * 8;
    int r = (int)(idx8 >> 11), k = (int)(idx8 & 2047);
    int g = r >> 6, j = r & 63;
    int srcr = (j < 32) ? (g * 32 + j) : (IM + g * 32 + (j - 32));
    cvt8(&w_gu[(size_t)srcr * HID + k], d_gu + idx8);
  } else if (gid < CV_DN_END) {
    size_t idx8 = (gid - CV_GU_END) * 8;
    cvt8(w_dn + idx8, d_dn + idx8);
  }
}

// ---------------- pipelined BMx256 GEMM body (R5/R8/R11 known-good structure) ----------------
// C[M,N] = A[M,K] * W[N,K]^T, M fixed 4096. 512 thr = 8 waves (2M x 4N).
// One barrier + one vmcnt(0) per K-tile (waited loads issued a full tile earlier);
// ds_reads interleaved with MFMA clusters; no intra-tile barriers -> waves drift.
// GEMM levers CLOSED by measurement: R6/R7/R10 structured schedules lost; R11
// setprio neutral; R13 32x32x16 shape swap regressed. This loop is the ceiling.
template <int EPI, int BM>
__device__ __forceinline__ void gemm_body(int bid, int ngb,
    const unsigned short* __restrict__ A, const unsigned short* __restrict__ W,
    int K, int ldo, void* __restrict__ outp, const float* __restrict__ resid) {
  constexpr int MREP  = BM / 32;
  constexpr int ABYT  = BM * 128;
  constexpr int BUFB  = ABYT + 32768;
  constexpr int NTM   = 4096 / BM;
  __shared__ __align__(16) char smem[2 * BUFB];
  const int t = threadIdx.x;
  const int w = t >> 6, l = t & 63;
  const int lr = l & 15, hi = l >> 4;
  const int wr = w >> 2, wc = w & 3;

  // T1: bijective XCD swizzle over tn-major enumeration (ngb % 8 == 0)
  const int q = ngb >> 3;
  const int id2 = (bid & 7) * q + (bid >> 3);
  const int tn = id2 / NTM, tm = id2 % NTM;
  const int m0b = tm * BM, n0b = tn << 8;

  // staging lane constants; source col pre-swizzled (byte bits 5,6 <- row bits 2,3)
  const int srow = t >> 3;
  const int scole = ((t & 7) << 3) ^ ((t & 32) ? 16 : 0) ^ ((t & 64) ? 32 : 0);
  const unsigned short* Ag = A + (size_t)(m0b + srow) * K + scole;
  const unsigned short* Wg = W + (size_t)(n0b + srow) * K + scole;
  const int ldsw = w * 1024;

  // ds_read swizzled byte bases per kk
  const int fa = ((lr & 4) ? 32 : 0) | ((lr & 8) ? 64 : 0);
  const int arow = (wr * (BM / 2) + lr) * 128 + hi * 16;
  const int brow = (wc * 64 + lr) * 128 + hi * 16;
  const int aoff0 = arow ^ fa, aoff1 = (arow + 64) ^ fa;
  const int boff0 = brow ^ fa, boff1 = (brow + 64) ^ fa;

#define ISSUE_A(jt, bb) do {                                                    \
    _Pragma("unroll")                                                           \
    for (int p_ = 0; p_ < BM / 64; ++p_)                                        \
      GLL(Ag + (size_t)(p_ * 64) * K + (size_t)(jt) * 64,                       \
          smem + (bb) * BUFB + p_ * 8192 + ldsw); } while (0)
#define ISSUE_B(jt, bb) do {                                                    \
    _Pragma("unroll")                                                           \
    for (int p_ = 0; p_ < 4; ++p_)                                              \
      GLL(Wg + (size_t)(p_ * 64) * K + (size_t)(jt) * 64,                       \
          smem + (bb) * BUFB + ABYT + p_ * 8192 + ldsw); } while (0)

#define RDF(off, base) (*(const bf16x8*)((base) + (off)))
#define MF(P, x, y, c0, c1, c2, c3) do {                                                     \
    acc[2*(P)  ][0] = __builtin_amdgcn_mfma_f32_16x16x32_bf16((x),(c0),acc[2*(P)  ][0],0,0,0);\
    acc[2*(P)+1][0] = __builtin_amdgcn_mfma_f32_16x16x32_bf16((y),(c0),acc[2*(P)+1][0],0,0,0);\
    acc[2*(P)  ][1] = __builtin_amdgcn_mfma_f32_16x16x32_bf16((x),(c1),acc[2*(P)  ][1],0,0,0);\
    acc[2*(P)+1][1] = __builtin_amdgcn_mfma_f32_16x16x32_bf16((y),(c1),acc[2*(P)+1][1],0,0,0);\
    acc[2*(P)  ][2] = __builtin_amdgcn_mfma_f32_16x16x32_bf16((x),(c2),acc[2*(P)  ][2],0,0,0);\
    acc[2*(P)+1][2] = __builtin_amdgcn_mfma_f32_16x16x32_bf16((y),(c2),acc[2*(P)+1][2],0,0,0);\
    acc[2*(P)  ][3] = __builtin_amdgcn_mfma_f32_16x16x32_bf16((x),(c3),acc[2*(P)  ][3],0,0,0);\
    acc[2*(P)+1][3] = __builtin_amdgcn_mfma_f32_16x16x32_bf16((y),(c3),acc[2*(P)+1][3],0,0,0);\
    } while (0)

  f32x4 acc[MREP][4];
#pragma unroll
  for (int m = 0; m < MREP; m++)
#pragma unroll
    for (int n = 0; n < 4; n++) acc[m][n] = (f32x4){0.f, 0.f, 0.f, 0.f};

  const int nkt = K >> 6;
  // prologue: stage tile 0 into buf 0
  ISSUE_A(0, 0); ISSUE_B(0, 0);

  for (int j = 0; j < nkt; ++j) {
    const int cur = j & 1;
    const char* Ab = smem + cur * BUFB;
    const char* Bb = Ab + ABYT;
    asm volatile("s_waitcnt vmcnt(0)" ::: "memory");   // waits loads issued a full tile ago
    __builtin_amdgcn_s_barrier();                       // all waves' slices resident (WAR-safe)
    __builtin_amdgcn_sched_barrier(0);
    if (j + 1 < nkt) { ISSUE_A(j + 1, cur ^ 1); ISSUE_B(j + 1, cur ^ 1); }
    bf16x8 b0 = RDF(boff0, Bb), b1 = RDF(boff0 + 2048, Bb),
           b2 = RDF(boff0 + 4096, Bb), b3 = RDF(boff0 + 6144, Bb);
    bf16x8 af0 = RDF(aoff0, Ab), af1 = RDF(aoff0 + 2048, Ab);
    bf16x8 af2, af3, b4, b5, b6, b7;
    if constexpr (MREP == 8) {
      af2 = RDF(aoff0 + 4096, Ab); af3 = RDF(aoff0 + 6144, Ab);
      MF(0, af0, af1, b0, b1, b2, b3);
      af0 = RDF(aoff0 + 8192, Ab); af1 = RDF(aoff0 + 10240, Ab);
      MF(1, af2, af3, b0, b1, b2, b3);
      af2 = RDF(aoff0 + 12288, Ab); af3 = RDF(aoff0 + 14336, Ab);
      MF(2, af0, af1, b0, b1, b2, b3);
      b4 = RDF(boff1, Bb); b5 = RDF(boff1 + 2048, Bb);
      b6 = RDF(boff1 + 4096, Bb); b7 = RDF(boff1 + 6144, Bb);
      af0 = RDF(aoff1, Ab); af1 = RDF(aoff1 + 2048, Ab);
      MF(3, af2, af3, b0, b1, b2, b3);
      af2 = RDF(aoff1 + 4096, Ab); af3 = RDF(aoff1 + 6144, Ab);
      MF(0, af0, af1, b4, b5, b6, b7);
      af0 = RDF(aoff1 + 8192, Ab); af1 = RDF(aoff1 + 10240, Ab);
      MF(1, af2, af3, b4, b5, b6, b7);
      af2 = RDF(aoff1 + 12288, Ab); af3 = RDF(aoff1 + 14336, Ab);
      MF(2, af0, af1, b4, b5, b6, b7);
      MF(3, af2, af3, b4, b5, b6, b7);
    } else {
      af2 = RDF(aoff0 + 4096, Ab); af3 = RDF(aoff0 + 6144, Ab);
      MF(0, af0, af1, b0, b1, b2, b3);
      b4 = RDF(boff1, Bb); b5 = RDF(boff1 + 2048, Bb);
      b6 = RDF(boff1 + 4096, Bb); b7 = RDF(boff1 + 6144, Bb);
      af0 = RDF(aoff1, Ab); af1 = RDF(aoff1 + 2048, Ab);
      MF(1, af2, af3, b0, b1, b2, b3);
      af2 = RDF(aoff1 + 4096, Ab); af3 = RDF(aoff1 + 6144, Ab);
      MF(0, af0, af1, b4, b5, b6, b7);
      MF(1, af2, af3, b4, b5, b6, b7);
    }
  }

  if constexpr (EPI == 0) {
    unsigned short* op = (unsigned short*)outp;
#pragma unroll
    for (int m = 0; m < MREP; m++)
#pragma unroll
      for (int n = 0; n < 4; n++)
#pragma unroll
        for (int r = 0; r < 4; r++) {
          int row = m0b + wr * (BM / 2) + m * 16 + hi * 4 + r;
          int col = n0b + wc * 64 + n * 16 + lr;
          op[(size_t)row * ldo + col] = f2bf(acc[m][n][r]);
        }
  } else if constexpr (EPI == 2) {
    unsigned short* op = (unsigned short*)outp;
    const int gbase = (n0b + wc * 64) >> 1;
#pragma unroll
    for (int m = 0; m < MREP; m++)
#pragma unroll
      for (int n = 0; n < 2; n++)
#pragma unroll
        for (int r = 0; r < 4; r++) {
          int row = m0b + wr * (BM / 2) + m * 16 + hi * 4 + r;
          int col = gbase + n * 16 + lr;
          float g = acc[m][n][r], u = acc[m][n + 2][r];
          op[(size_t)row * ldo + col] = f2bf(siluf(g) * u);
        }
  } else {
    float* op = (float*)outp;
#pragma unroll
    for (int m = 0; m < MREP; m++)
#pragma unroll
      for (int n = 0; n < 4; n++)
#pragma unroll
        for (int r = 0; r < 4; r++) {
          int row = m0b + wr * (BM / 2) + m * 16 + hi * 4 + r;
          int col = n0b + wc * 64 + n * 16 + lr;
          float v = acc[m][n][r];
          if constexpr (EPI == 1) v += resid[(size_t)row * ldo + col];
          op[(size_t)row * ldo + col] = v;
        }
  }
#undef ISSUE_A
#undef ISSUE_B
#undef RDF
#undef MF
}

template <int EPI, int BM>
__global__ __launch_bounds__(512, 2)
void gemm8(const unsigned short* __restrict__ A, const unsigned short* __restrict__ W,
           int K, int ldo, void* __restrict__ outp, const float* __restrict__ resid) {
  gemm_body<EPI, BM>((int)blockIdx.x, (int)gridDim.x, A, W, K, ldo, outp, resid);
}

// in_proj GEMM fused with out/gu/dn weight conversion: blocks [0,ngb) do GEMM
// tiles, blocks [ngb, ...) stream the f32->bf16 conversions (backfill CUs as
// GEMM tiles retire; cvt uses the ~5 TB/s of HBM headroom the GEMM leaves).
__global__ __launch_bounds__(512, 2)
void k_inproj_fused(const unsigned short* __restrict__ A, const unsigned short* __restrict__ Wbf,
                    int ngb, unsigned short* __restrict__ projbf,
                    const float* __restrict__ w_out, const float* __restrict__ w_gu,
                    const float* __restrict__ w_dn, unsigned short* __restrict__ d_out,
                    unsigned short* __restrict__ d_gu, unsigned short* __restrict__ d_dn) {
  if ((int)blockIdx.x < ngb) {
    gemm_body<0, 256>((int)blockIdx.x, ngb, A, Wbf, HID, DPADR, projbf, nullptr);
  } else {
    size_t gid = CV_IN_END + (size_t)((int)blockIdx.x - ngb) * 512 + threadIdx.x;
    cvt_do(gid, nullptr, w_out, w_gu, w_dn, nullptr, d_out, d_gu, d_dn);
  }
}

// ---------------- norms ----------------
__device__ __forceinline__ float block_reduce_sum256(float v, float* sred) {
#pragma unroll
  for (int m = 32; m; m >>= 1) v += __shfl_xor(v, m);
  int t = threadIdx.x;
  if ((t & 63) == 0) sred[t >> 6] = v;
  __syncthreads();
  return sred[0] + sred[1] + sred[2] + sred[3];
}

// addnorm fused with in_proj weight conversion (blocks >= T_TOK do cvt)
__global__ __launch_bounds__(256)
void k_addnorm(const float* __restrict__ hin, const float* __restrict__ rin,
               const float* __restrict__ wln, float* __restrict__ rout,
               unsigned short* __restrict__ hbf,
               const float* __restrict__ w_in, unsigned short* __restrict__ d_in) {
  if ((int)blockIdx.x >= T_TOK) {
    size_t gid = (size_t)((int)blockIdx.x - T_TOK) * 256 + threadIdx.x;
    cvt_do(gid, w_in, nullptr, nullptr, nullptr, d_in, nullptr, nullptr, nullptr);
    return;
  }
  __shared__ float sred[4];
  const int tok = blockIdx.x, t = threadIdx.x;
  const size_t base = (size_t)tok * HID + t * 8;
  float4 a0 = *(const float4*)&hin[base];
  float4 a1 = *(const float4*)&hin[base + 4];
  float4 b0 = *(const float4*)&rin[base];
  float4 b1 = *(const float4*)&rin[base + 4];
  float v[8] = {a0.x + b0.x, a0.y + b0.y, a0.z + b0.z, a0.w + b0.w,
                a1.x + b1.x, a1.y + b1.y, a1.z + b1.z, a1.w + b1.w};
  float ss = 0.f;
#pragma unroll
  for (int j = 0; j < 8; j++) ss += v[j] * v[j];
  float tot = block_reduce_sum256(ss, sred);
  float rms = rsqrtf(tot * (1.f / HID) + 1e-5f);
  *(float4*)&rout[base] = (float4){v[0], v[1], v[2], v[3]};
  *(float4*)&rout[base + 4] = (float4){v[4], v[5], v[6], v[7]};
  float4 w0 = *(const float4*)&wln[t * 8];
  float4 w1 = *(const float4*)&wln[t * 8 + 4];
  float wa[8] = {w0.x, w0.y, w0.z, w0.w, w1.x, w1.y, w1.z, w1.w};
  unsigned short o[8];
#pragma unroll
  for (int j = 0; j < 8; j++) o[j] = f2bf(v[j] * rms * wa[j]);
  *(ushort4*)&hbf[base] = *(ushort4*)&o[0];
  *(ushort4*)&hbf[base + 4] = *(ushort4*)&o[4];
}

__global__ __launch_bounds__(256)
void k_rmsnorm_bf(const float* __restrict__ src, const float* __restrict__ wln,
                  unsigned short* __restrict__ dst) {
  __shared__ float sred[4];
  const int tok = blockIdx.x, t = threadIdx.x;
  const size_t base = (size_t)tok * HID + t * 8;
  float4 a0 = *(const float4*)&src[base];
  float4 a1 = *(const float4*)&src[base + 4];
  float v[8] = {a0.x, a0.y, a0.z, a0.w, a1.x, a1.y, a1.z, a1.w};
  float ss = 0.f;
#pragma unroll
  for (int j = 0; j < 8; j++) ss += v[j] * v[j];
  float tot = block_reduce_sum256(ss, sred);
  float rms = rsqrtf(tot * (1.f / HID) + 1e-5f);
  float4 w0 = *(const float4*)&wln[t * 8];
  float4 w1 = *(const float4*)&wln[t * 8 + 4];
  float wa[8] = {w0.x, w0.y, w0.z, w0.w, w1.x, w1.y, w1.z, w1.w};
  unsigned short o[8];
#pragma unroll
  for (int j = 0; j < 8; j++) o[j] = f2bf(v[j] * rms * wa[j]);
  *(ushort4*)&dst[base] = *(ushort4*)&o[0];
  *(ushort4*)&dst[base + 4] = *(ushort4*)&o[4];
}

__global__ __launch_bounds__(256)
void k_gatenorm(const unsigned short* __restrict__ ybuf, const unsigned short* __restrict__ projbf,
                const float* __restrict__ wmix, unsigned short* __restrict__ ynorm) {
  __shared__ float sred[4];
  const int tok = blockIdx.x, t = threadIdx.x;
  const size_t yb = (size_t)tok * DI;
  const size_t pb = (size_t)tok * DPADR;
  float g[16];
  float ss = 0.f;
#pragma unroll
  for (int j = 0; j < 16; j++) {
    int idx = j * 256 + t;
    float yv = bf2f(ybuf[yb + idx]);
    float z = bf2f(projbf[pb + idx]);
    float gg = yv * siluf(z);
    g[j] = gg;
    ss += gg * gg;
  }
  float tot = block_reduce_sum256(ss, sred);
  float rms = rsqrtf(tot * (1.f / DI) + 1e-5f);
#pragma unroll
  for (int j = 0; j < 16; j++) {
    int idx = j * 256 + t;
    ynorm[yb + idx] = f2bf(g[j] * rms * wmix[idx]);
  }
}

// ---------------- conv (depthwise causal K=4) + silu + fused dt softplus ----------------
__global__ __launch_bounds__(256)
void k_conv(const unsigned short* __restrict__ projbf, const float* __restrict__ cw,
            const float* __restrict__ cb, const float* __restrict__ dt_bias,
            unsigned short* __restrict__ xbf, unsigned short* __restrict__ bcbf,
            float* __restrict__ dtg) {
  const int c = blockIdx.x * 256 + threadIdx.x;   // 0..4607
  const int tk = blockIdx.y;                      // token
  if (c < CONVD) {
    const int lpos = tk & (LSEQ - 1);
    float4 wv = *(const float4*)&cw[c * 4];
    float wk[4] = {wv.x, wv.y, wv.z, wv.w};
    float acc = cb[c];
#pragma unroll
    for (int k = 0; k < 4; k++) {
      int lp = lpos - 3 + k;
      if (lp >= 0) acc += bf2f(projbf[(size_t)(tk - 3 + k) * DPADR + DI + c]) * wk[k];
    }
    unsigned short r = f2bf(siluf(acc));
    if (c < DI) xbf[(size_t)tk * DI + c] = r;
    else        bcbf[(size_t)tk * 256 + (c - DI)] = r;
  } else if (c < CONVD + NH) {
    const int hh = c - CONVD;
    float x = bf2f(projbf[(size_t)tk * DPADR + DI + c]) + dt_bias[hh];
    float dt = (x > 20.f) ? x : log1pf(__expf(x));
    dtg[(size_t)tk * NH + hh] = dt;
  }
}

// ---------------- SSD kernel 1: per (b,h,chunk) intra + chunk-state ----------------
__global__ __launch_bounds__(256)
void k_ssd1(const unsigned short* __restrict__ xbf, const unsigned short* __restrict__ bcbf,
            const float* __restrict__ dtg, const float* __restrict__ A_log,
            const float* __restrict__ Dv, unsigned short* __restrict__ ybuf,
            unsigned short* __restrict__ Sc, float* __restrict__ dtsum) {
  __shared__ __align__(16) char smem[60928];
  unsigned short* sBs  = (unsigned short*)(smem);          // [64][128]
  unsigned short* sCs  = (unsigned short*)(smem + 16384);  // [64][128]
  unsigned short* sMs  = (unsigned short*)(smem + 16384);  // alias: [64][72]
  unsigned short* sBsT = (unsigned short*)(smem + 32768);  // [128][72] scaled B^T
  unsigned short* sXsT = (unsigned short*)(smem + 51200);  // [64][72]  x^T
  float* sdt = (float*)(smem + 60416);
  float* sdl = (float*)(smem + 60672);

  const int bi = blockIdx.x;
  const int ch = bi & 31, h = (bi >> 5) & 63, b = bi >> 11;
  const int bh = b * NH + h;
  const int tok0 = b * LSEQ + ch * QC;
  const int t = threadIdx.x;
  const int w = t >> 6, l = t & 63, lr = l & 15, hi = l >> 4;
  const float Ah = -__expf(A_log[h]);
  const float Dh = Dv[h];

  {
    const int srow = t >> 4, scol = (t & 15) * 8;
#pragma unroll
    for (int i = 0; i < 4; i++) {
      const unsigned short* gb = bcbf + (size_t)(tok0 + srow + 16 * i) * 256 + scol;
      GLL(gb, (char*)sBs + i * 4096 + w * 1024);
      GLL(gb + 128, (char*)sCs + i * 4096 + w * 1024);
    }
  }
  if (t < QC) sdt[t] = dtg[(size_t)(tok0 + t) * NH + h];
  __syncthreads();
  if (t < QC) sdl[t] = sdt[t];
  __syncthreads();
  for (int off = 1; off < QC; off <<= 1) {
    float v = 0.f;
    if (t < QC && t >= off) v = sdl[t - off];
    __syncthreads();
    if (t < QC) sdl[t] += v;
    __syncthreads();
  }

  {
    const int s = t >> 2;
    const float DlQ = sdl[QC - 1];
    const float csc = __expf(Ah * (DlQ - sdl[s])) * sdt[s];
    const int n0 = (t & 3) * 32;
#pragma unroll
    for (int j = 0; j < 32; j++) {
      float bv = bf2f(sBs[s * 128 + n0 + j]);
      sBsT[(n0 + j) * 72 + s] = f2bf(csc * bv);
    }
    const int p0 = (t & 3) * 16;
    const unsigned short* gx = xbf + (size_t)(tok0 + s) * DI + h * 64 + p0;
    union { uint4 v; unsigned short u[8]; } x0, x1;
    x0.v = *(const uint4*)gx;
    x1.v = *(const uint4*)(gx + 8);
#pragma unroll
    for (int j = 0; j < 8; j++) {
      sXsT[(p0 + j) * 72 + s] = x0.u[j];
      sXsT[(p0 + 8 + j) * 72 + s] = x1.u[j];
    }
  }
  __syncthreads();

  f32x4 accS[4];
#pragma unroll
  for (int jf = 0; jf < 4; jf++) accS[jf] = (f32x4){0.f, 0.f, 0.f, 0.f};
#pragma unroll
  for (int ks = 0; ks < 4; ks++) {
    bf16x8 a = *(const bf16x8*)&sBs[(w * 16 + lr) * 128 + ks * 32 + hi * 8];
#pragma unroll
    for (int jf = 0; jf < 4; jf++) {
      bf16x8 bbq = *(const bf16x8*)&sCs[(jf * 16 + lr) * 128 + ks * 32 + hi * 8];
      accS[jf] = __builtin_amdgcn_mfma_f32_16x16x32_bf16(a, bbq, accS[jf], 0, 0, 0);
    }
  }
  __syncthreads();

  {
    const int s0 = w * 16 + hi * 4;
#pragma unroll
    for (int jf = 0; jf < 4; jf++) {
      const int tt = jf * 16 + lr;
      const float dlt = sdl[tt];
      unsigned short mv[4];
#pragma unroll
      for (int r = 0; r < 4; r++) {
        const int ss = s0 + r;
        float val = 0.f;
        if (ss <= tt) val = accS[jf][r] * __expf(Ah * (dlt - sdl[ss])) * sdt[ss];
        mv[r] = f2bf(val);
      }
      *(ushort4*)&sMs[tt * 72 + s0] = *(ushort4*)mv;
    }
  }
  __syncthreads();

  {
    f32x4 accY[4];
#pragma unroll
    for (int jf = 0; jf < 4; jf++) accY[jf] = (f32x4){0.f, 0.f, 0.f, 0.f};
#pragma unroll
    for (int ks = 0; ks < 2; ks++) {
      bf16x8 a = *(const bf16x8*)&sMs[(w * 16 + lr) * 72 + ks * 32 + hi * 8];
#pragma unroll
      for (int jf = 0; jf < 4; jf++) {
        bf16x8 bbq = *(const bf16x8*)&sXsT[(jf * 16 + lr) * 72 + ks * 32 + hi * 8];
        accY[jf] = __builtin_amdgcn_mfma_f32_16x16x32_bf16(a, bbq, accY[jf], 0, 0, 0);
      }
    }
#pragma unroll
    for (int jf = 0; jf < 4; jf++)
#pragma unroll
      for (int r = 0; r < 4; r++) {
        const int tt = w * 16 + hi * 4 + r;
        const int pp = jf * 16 + lr;
        float xv = bf2f(sXsT[pp * 72 + tt]);
        ybuf[(size_t)(tok0 + tt) * DI + h * 64 + pp] = f2bf(accY[jf][r] + Dh * xv);
      }
  }

  {
    f32x4 accT[8];
#pragma unroll
    for (int jf = 0; jf < 8; jf++) accT[jf] = (f32x4){0.f, 0.f, 0.f, 0.f};
#pragma unroll
    for (int ks = 0; ks < 2; ks++) {
      bf16x8 a = *(const bf16x8*)&sXsT[(w * 16 + lr) * 72 + ks * 32 + hi * 8];
#pragma unroll
      for (int jf = 0; jf < 8; jf++) {
        bf16x8 bbq = *(const bf16x8*)&sBsT[(jf * 16 + lr) * 72 + ks * 32 + hi * 8];
        accT[jf] = __builtin_amdgcn_mfma_f32_16x16x32_bf16(a, bbq, accT[jf], 0, 0, 0);
      }
    }
    unsigned short* sc = Sc + ((size_t)bh * NCH + ch) * (PDIM * NSTATE);
#pragma unroll
    for (int jf = 0; jf < 8; jf++)
#pragma unroll
      for (int r = 0; r < 4; r++) {
        const int pp = w * 16 + hi * 4 + r;
        const int nn = jf * 16 + lr;
        sc[pp * NSTATE + nn] = f2bf(accT[jf][r]);
      }
  }
  if (t == 0) dtsum[bh * NCH + ch] = sdl[QC - 1];
}

// ---------------- SSD kernel 2: serial chunk-state combine ----------------
__global__ __launch_bounds__(256)
void k_ssd2(const float* __restrict__ A_log, const float* __restrict__ dtsum,
            unsigned short* __restrict__ ScHt) {
  const int blk = blockIdx.x;
  const int bh = blk >> 3, pg = blk & 7;
  const int t = threadIdx.x;
  const int p = pg * 8 + (t >> 5), n0 = (t & 31) * 4;
  const int h = bh & 63;
  const float Ah = -__expf(A_log[h]);
  float H[4] = {0.f, 0.f, 0.f, 0.f};
  for (int c = 0; c < NCH; c++) {
    size_t base = (((size_t)bh * NCH + c) * PDIM + p) * NSTATE + n0;
    ushort4 sv = *(const ushort4*)&ScHt[base];
    float dec = __expf(Ah * dtsum[bh * NCH + c]);
    ushort4 hv;
    hv.x = f2bf(H[0]); hv.y = f2bf(H[1]); hv.z = f2bf(H[2]); hv.w = f2bf(H[3]);
    *(ushort4*)&ScHt[base] = hv;
    H[0] = dec * H[0] + bf2f(sv.x);
    H[1] = dec * H[1] + bf2f(sv.y);
    H[2] = dec * H[2] + bf2f(sv.z);
    H[3] = dec * H[3] + bf2f(sv.w);
  }
}

// ---------------- SSD kernel 3: inter-chunk Y += decay * C @ H_in ----------------
__global__ __launch_bounds__(256)
void k_ssd3(const unsigned short* __restrict__ bcbf, const unsigned short* __restrict__ Ht,
            const float* __restrict__ dtg, const float* __restrict__ A_log,
            unsigned short* __restrict__ ybuf) {
  __shared__ __align__(16) char smem[33280];
  unsigned short* sCs = (unsigned short*)(smem);
  unsigned short* sHt = (unsigned short*)(smem + 16384);
  float* sdt = (float*)(smem + 32768);
  float* sdl = (float*)(smem + 33024);

  const int bi = blockIdx.x;
  const int ch = bi & 31, h = (bi >> 5) & 63, b = bi >> 11;
  const int bh = b * NH + h;
  const int tok0 = b * LSEQ + ch * QC;
  const int t = threadIdx.x;
  const int w = t >> 6, l = t & 63, lr = l & 15, hi = l >> 4;
  const float Ah = -__expf(A_log[h]);

  {
    const int srow = t >> 4, scol = (t & 15) * 8;
    const unsigned short* gh = Ht + ((size_t)bh * NCH + ch) * (PDIM * NSTATE);
#pragma unroll
    for (int i = 0; i < 4; i++) {
      const unsigned short* gc = bcbf + (size_t)(tok0 + srow + 16 * i) * 256 + 128 + scol;
      GLL(gc, (char*)sCs + i * 4096 + w * 1024);
      GLL(gh + i * 2048 + t * 8, (char*)sHt + i * 4096 + w * 1024);
    }
  }
  if (t < QC) sdt[t] = dtg[(size_t)(tok0 + t) * NH + h];
  __syncthreads();
  if (t < QC) sdl[t] = sdt[t];
  __syncthreads();
  for (int off = 1; off < QC; off <<= 1) {
    float v = 0.f;
    if (t < QC && t >= off) v = sdl[t - off];
    __syncthreads();
    if (t < QC) sdl[t] += v;
    __syncthreads();
  }

  f32x4 acc[4];
#pragma unroll
  for (int jf = 0; jf < 4; jf++) acc[jf] = (f32x4){0.f, 0.f, 0.f, 0.f};
#pragma unroll
  for (int ks = 0; ks < 4; ks++) {
    bf16x8 a = *(const bf16x8*)&sCs[(w * 16 + lr) * 128 + ks * 32 + hi * 8];
#pragma unroll
    for (int jf = 0; jf < 4; jf++) {
      bf16x8 bbq = *(const bf16x8*)&sHt[(jf * 16 + lr) * 128 + ks * 32 + hi * 8];
      acc[jf] = __builtin_amdgcn_mfma_f32_16x16x32_bf16(a, bbq, acc[jf], 0, 0, 0);
    }
  }
#pragma unroll
  for (int jf = 0; jf < 4; jf++)
#pragma unroll
    for (int r = 0; r < 4; r++) {
      const int tt = w * 16 + hi * 4 + r;
      const int pp = jf * 16 + lr;
      const float dec = __expf(Ah * sdl[tt]);
      const size_t o = (size_t)(tok0 + tt) * DI + h * 64 + pp;
      ybuf[o] = f2bf(bf2f(ybuf[o]) + dec * acc[jf][r]);
    }
}

// ---------------- workspace layout (bytes), total ~412.1 MB ----------------
static const size_t OFF_WBF_IN  = 0;
static const size_t OFF_WBF_OUT = 35651584;
static const size_t OFF_WBF_GU  = 52428800;
static const size_t OFF_WBF_DN  = 119537664;
static const size_t OFF_RESID   = 153092096;
static const size_t OFF_HSBF    = 186646528;
static const size_t OFF_PROJ    = 203423744;
static const size_t OFF_XBF     = 274726912;
static const size_t OFF_BCBF    = 308281344;
static const size_t OFF_DTG     = 310378496;
static const size_t OFF_YBUF    = 311427072;
static const size_t OFF_SC      = 344981504;
static const size_t OFF_DTSUM   = 412090368;

extern "C" void kernel_launch(void* const* d_in, const int* in_sizes, int n_in,
                              void* d_out, int out_size, void* d_ws, size_t ws_size,
                              hipStream_t stream) {
  (void)in_sizes; (void)n_in; (void)out_size; (void)ws_size;
  const float* hidden   = (const float*)d_in[1];
  const float* resin    = (const float*)d_in[2];
  const float* w_inproj = (const float*)d_in[3];
  const float* conv_w   = (const float*)d_in[4];
  const float* conv_b   = (const float*)d_in[5];
  const float* A_log    = (const float*)d_in[6];
  const float* Dvec     = (const float*)d_in[7];
  const float* dt_bias  = (const float*)d_in[8];
  const float* w_mix    = (const float*)d_in[9];
  const float* w_outp   = (const float*)d_in[10];
  const float* w_ln1    = (const float*)d_in[11];
  const float* w_ln2    = (const float*)d_in[12];
  const float* w_gu     = (const float*)d_in[13];
  const float* w_dn     = (const float*)d_in[14];

  char* ws = (char*)d_ws;
  unsigned short* wbf_in  = (unsigned short*)(ws + OFF_WBF_IN);
  unsigned short* wbf_out = (unsigned short*)(ws + OFF_WBF_OUT);
  unsigned short* wbf_gu  = (unsigned short*)(ws + OFF_WBF_GU);
  unsigned short* wbf_dn  = (unsigned short*)(ws + OFF_WBF_DN);
  float*          residb  = (float*)(ws + OFF_RESID);
  unsigned short* hsbf    = (unsigned short*)(ws + OFF_HSBF);
  unsigned short* projbf  = (unsigned short*)(ws + OFF_PROJ);
  unsigned short* actbf   = (unsigned short*)(ws + OFF_PROJ);   // alias
  unsigned short* xbf     = (unsigned short*)(ws + OFF_XBF);
  unsigned short* ynormbf = (unsigned short*)(ws + OFF_XBF);    // alias
  unsigned short* bcbf    = (unsigned short*)(ws + OFF_BCBF);
  float*          dtgb    = (float*)(ws + OFF_DTG);
  unsigned short* ybuf    = (unsigned short*)(ws + OFF_YBUF);
  unsigned short* scht    = (unsigned short*)(ws + OFF_SC);
  float*          dtsumb  = (float*)(ws + OFF_DTSUM);

  float* out0 = (float*)d_out;
  float* res2 = out0 + (size_t)T_TOK * HID;

  // 1) residual add + input rmsnorm, fused with in_proj weight cvt
  k_addnorm<<<T_TOK + 8704, 256, 0, stream>>>(hidden, resin, w_ln1, residb, hsbf,
                                              w_inproj, wbf_in);
  // 2) in_proj GEMM (544 blocks) fused with out/gu/dn weight cvt (14336 blocks)
  k_inproj_fused<<<544 + 14336, 512, 0, stream>>>(hsbf, wbf_in, 544, projbf,
                                                  w_outp, w_gu, w_dn,
                                                  wbf_out, wbf_gu, wbf_dn);
  // 3) causal conv + silu -> xbf / bcbf (bf16), fused dt softplus
  k_conv<<<dim3(18, T_TOK), 256, 0, stream>>>(projbf, conv_w, conv_b, dt_bias, xbf, bcbf, dtgb);
  // 4) SSD intra + chunk states
  k_ssd1<<<4096, 256, 0, stream>>>(xbf, bcbf, dtgb, A_log, Dvec, ybuf, scht, dtsumb);
  // 5) SSD serial combine
  k_ssd2<<<1024, 256, 0, stream>>>(A_log, dtsumb, scht);
  // 6) SSD inter-chunk
  k_ssd3<<<4096, 256, 0, stream>>>(bcbf, scht, dtgb, A_log, ybuf);
  // 7) gate + mixer rmsnorm -> ynorm bf16
  k_gatenorm<<<T_TOK, 256, 0, stream>>>(ybuf, projbf, w_mix, ynormbf);
  // 8) out_proj GEMM + residual -> residual2 (output 1)
  gemm8<1, 128><<<8 * 32, 512, 0, stream>>>(ynormbf, wbf_out, DI, HID, res2, residb);
  // 9) pre-FF rmsnorm -> hs2 bf16
  k_rmsnorm_bf<<<T_TOK, 256, 0, stream>>>(res2, w_ln2, hsbf);
  // 10) gate_up GEMM (fused silu-pair epilogue) -> act bf16
  gemm8<2, 256><<<64 * 16, 512, 0, stream>>>(hsbf, wbf_gu, HID, IM, actbf, nullptr);
  // 11) down GEMM -> out (output 0)
  gemm8<3, 128><<<8 * 32, 512, 0, stream>>>(actbf, wbf_dn, IM, HID, out0, nullptr);
}